// Round 13
// baseline (18.983 us; speedup 1.0000x reference)
//
#include <hip/hip_runtime.h>

#define NSEG 16
#define BTHR 512

// ONE kernel, no workspace, no partials. Grid = B*NSEG*4 = 512 blocks
// (2 per CU), 512 threads (8 waves). Block (bs, q) computes the mean of its
// segment's rows over H-quarter q (256 floats): 8 row-groups x 64 threads;
// group g takes rows g+8k with 8-deep ILP, so per-CU in-flight stays
// ~128 KB (2 blocks x 8 waves x 8 KB) while the max block work halves
// vs R11 (256 rows x 1 KB = 256 KB) -> shorter indivisible tail.
// Deterministic: fixed row->group assignment + fixed pairwise trees.
__global__ void __launch_bounds__(BTHR, 4) k_pool(
        const float* __restrict__ x, const int* __restrict__ mask,
        float* __restrict__ out, float* __restrict__ mout,
        int L, int H) {
    int bid = blockIdx.x;              // bs*4 + q
    int q = bid & 3;
    int bs = bid >> 2;
    int b = bs >> 4, s = bs & 15;
    int t = threadIdx.x;               // 0..511
    int lane = t & 63, wid = t >> 6;   // 8 waves

    __shared__ int ish[8];
    __shared__ int vsh;
    __shared__ float4 red[8][64];      // 8 KB

    // ---- vl: block-reduce the 16 KB mask row (two int4 per thread) ----
    const int4* m4 = (const int4*)(mask + (size_t)b * L);
    int n4 = L >> 2;
    int acc = 0;
    for (int i = t; i < n4; i += BTHR) { int4 v = m4[i]; acc += v.x + v.y + v.z + v.w; }
    #pragma unroll
    for (int off = 32; off > 0; off >>= 1) acc += __shfl_down(acc, off, 64);
    if (lane == 0) ish[wid] = acc;
    __syncthreads();
    if (t == 0) {
        int v = 0;
        #pragma unroll
        for (int w = 0; w < 8; ++w) v += ish[w];
        vsh = v;
    }
    __syncthreads();
    int vl = vsh;

    // ---- segment geometry (exact integer boundaries) ----
    int start = (s * vl) >> 4;                       // s*vl < 2^24 -> exact
    int end   = ((s + 1) * vl) >> 4;                 // s==15 -> exactly vl
    int n = (start < vl) ? max(end - start, 1) : 0;  // rows to pool (<= 256)
    int cnt = max(end - start, 1);

    if (q == 0 && t == 0) mout[bs] = (start < vl) ? 1.0f : 0.0f;

    // ---- stream: group g, rows g+8k, 8-deep ILP over the H-quarter ----
    int g = t >> 6;                    // row-group 0..7
    int c = t & 63;                    // float4 column within quarter-row
    const float* base = x + ((size_t)b * L + start) * H + q * (H >> 2) + c * 4;

    float4 A[8];
    #pragma unroll
    for (int k = 0; k < 8; ++k) A[k] = make_float4(0.f, 0.f, 0.f, 0.f);

    for (int r0 = g; r0 < n; r0 += 64) {
        #pragma unroll
        for (int k = 0; k < 8; ++k) {
            int r = r0 + (k << 3);
            if (r < n) {               // uniform across the group's wave
                float4 v = *(const float4*)(base + (size_t)r * H);
                A[k].x += v.x; A[k].y += v.y; A[k].z += v.z; A[k].w += v.w;
            }
        }
    }

    // ---- fixed-order pairwise tree over the 8 ILP accumulators ----
    float4 o;
    o.x = ((A[0].x + A[1].x) + (A[2].x + A[3].x)) + ((A[4].x + A[5].x) + (A[6].x + A[7].x));
    o.y = ((A[0].y + A[1].y) + (A[2].y + A[3].y)) + ((A[4].y + A[5].y) + (A[6].y + A[7].y));
    o.z = ((A[0].z + A[1].z) + (A[2].z + A[3].z)) + ((A[4].z + A[5].z) + (A[6].z + A[7].z));
    o.w = ((A[0].w + A[1].w) + (A[2].w + A[3].w)) + ((A[4].w + A[5].w) + (A[6].w + A[7].w));
    red[g][c] = o;
    __syncthreads();

    // ---- fixed-order tree over the 8 row-groups, scale, write ----
    if (t < 64) {
        float4 r0 = red[0][t], r1 = red[1][t], r2 = red[2][t], r3 = red[3][t];
        float4 r4 = red[4][t], r5 = red[5][t], r6 = red[6][t], r7 = red[7][t];
        float4 p;
        p.x = ((r0.x + r1.x) + (r2.x + r3.x)) + ((r4.x + r5.x) + (r6.x + r7.x));
        p.y = ((r0.y + r1.y) + (r2.y + r3.y)) + ((r4.y + r5.y) + (r6.y + r7.y));
        p.z = ((r0.z + r1.z) + (r2.z + r3.z)) + ((r4.z + r5.z) + (r6.z + r7.z));
        p.w = ((r0.w + r1.w) + (r2.w + r3.w)) + ((r4.w + r5.w) + (r6.w + r7.w));
        float scl = 1.0f / (float)cnt;   // n==0 -> all zeros -> writes 0
        p.x *= scl; p.y *= scl; p.z *= scl; p.w *= scl;
        *(float4*)(out + (size_t)bs * H + q * (H >> 2) + t * 4) = p;
    }
}

extern "C" void kernel_launch(void* const* d_in, const int* in_sizes, int n_in,
                              void* d_out, int out_size, void* d_ws, size_t ws_size,
                              hipStream_t stream) {
    const float* hs  = (const float*)d_in[0];
    const int* mask  = (const int*)d_in[1];
    int H = in_sizes[0] / in_sizes[1];          // 1024
    int B = out_size / (NSEG * (H + 1));        // 8
    int L = in_sizes[1] / B;                    // 4096

    float* seg_out  = (float*)d_out;
    float* mask_out = seg_out + (size_t)B * NSEG * H;

    k_pool<<<B * NSEG * 4, BTHR, 0, stream>>>(hs, mask, seg_out, mask_out, L, H);
}